// Round 1
// 72.438 us; speedup vs baseline: 1.0388x; 1.0388x over previous
//
#include <hip/hip_runtime.h>

#define KCENT 128
#define BLOCK 256
#define TN    512                  // table nodes (8 KB LDS as float4)
#define YMIN  (-9.0f)
#define YMAX  (9.0f)

#if __has_builtin(__builtin_amdgcn_exp2f)
#define EXP2F(x) __builtin_amdgcn_exp2f(x)
#else
#define EXP2F(x) exp2f(x)
#endif

// F(y) = sum_k w_k exp(-((y-c_k)g_k)^2) and F'(y) are 1-D in y: kernel 1
// tabulates (F, F', dF, dF') at 512 nodes (one wave per node, lanes split
// centers, shfl_xor reduce); kernel 2 does one LDS interp + ~25 fma per elem.
// TN=512: interp err ~0.022 in F -> ~2.3e-7 in output (threshold 2.1e-4).
// R4: rocprof top-5 = only 256MiB ws-poison fills (40us each) -> our kernels
// are each <40us and modeled at ~8us combined; dur_us is mostly harness floor.
// This round: 4 elems/thread (1024 blocks, 4-way ILP, staging traffic halved)
// to shrink the controllable slice; if dur_us barely moves, M1 confirmed.

__global__ __launch_bounds__(256) void build_table_kernel(
    const float* __restrict__ centers,
    const float* __restrict__ gammas,
    const float* __restrict__ weights,
    float4* __restrict__ tab)
{
    const int gid  = blockIdx.x * blockDim.x + threadIdx.x;
    const int node = gid >> 6;
    const int lane = gid & 63;
    if (node >= TN) return;
    const float SQRT_LOG2E = 1.2011224087864498f;  // sqrt(log2 e)
    const float TWO_LN2    = 1.3862943611198906f;  // 2 ln 2
    const float h  = (YMAX - YMIN) / (float)(TN - 1);
    const float y0 = YMIN + node * h;
    const float y1 = y0 + h;
    float F0 = 0.f, P0 = 0.f, F1 = 0.f, P1 = 0.f;
    #pragma unroll
    for (int kk = 0; kk < KCENT / 64; ++kk) {
        const int k = lane + kk * 64;
        float g  = gammas[k];
        float w  = weights[k];
        float a  = g * SQRT_LOG2E;
        float b  = a * centers[k];
        float w2 = -TWO_LN2 * a * w;
        float x0 = __builtin_fmaf(a, y0, -b);
        float p0 = EXP2F(-(x0 * x0));
        F0 = __builtin_fmaf(w, p0, F0);
        P0 = __builtin_fmaf(w2, x0 * p0, P0);
        float x1 = __builtin_fmaf(a, y1, -b);
        float p1 = EXP2F(-(x1 * x1));
        F1 = __builtin_fmaf(w, p1, F1);
        P1 = __builtin_fmaf(w2, x1 * p1, P1);
    }
    #pragma unroll
    for (int off = 32; off > 0; off >>= 1) {
        F0 += __shfl_xor(F0, off);
        P0 += __shfl_xor(P0, off);
        F1 += __shfl_xor(F1, off);
        P1 += __shfl_xor(P1, off);
    }
    if (lane == 0) tab[node] = make_float4(F0, P0, F1 - F0, P1 - P0);
}

__device__ __forceinline__ float2 rk4_elem(float u, float yy,
                                           const float4* sT, float INVH) {
    float tpos = (yy - YMIN) * INVH;
    int idx = (int)tpos;
    idx = idx < 0 ? 0 : (idx > TN - 2 ? TN - 2 : idx);
    float fr = tpos - (float)idx;
    float4 n = sT[idx];
    float F  = __builtin_fmaf(fr, n.z, n.x);
    float Fp = __builtin_fmaf(fr, n.w, n.y);

    const float INV95 = 1.0f / 95.45f;
    float s1 = (yy > 0.f) ? 1.f : ((yy < 0.f) ? -1.f : 0.f);
    float a1 = (u - yy * 214.9261f - 19.3607f * s1 - F + 3.2902f) * INV95;
    float dy = a1 * 0.001f;
    float h2 = 0.5f * dy;
    float y2 = yy + h2;             // k2 == k3 evaluation point
    float y4 = yy + dy;
    float rb2 = __builtin_fmaf(Fp, h2, F);   // 1st-order Taylor of F
    float rb4 = __builtin_fmaf(Fp, dy, F);
    float s2 = (y2 > 0.f) ? 1.f : ((y2 < 0.f) ? -1.f : 0.f);
    float a2 = (u - y2 * 214.9261f - 19.3607f * s2 - rb2 + 3.2902f) * INV95;
    float s4 = (y4 > 0.f) ? 1.f : ((y4 < 0.f) ? -1.f : 0.f);
    float a4 = (u - y4 * 214.9261f - 19.3607f * s4 - rb4 + 3.2902f) * INV95;

    const float DT6 = 0.001f / 6.0f;
    return make_float2(DT6 * (yy + 4.f * y2 + y4),
                       DT6 * (a1 + 4.f * a2 + a4));
}

__global__ __launch_bounds__(BLOCK) void rk4_tab_kernel(
    const float* __restrict__ inputs,
    const float* __restrict__ states,
    const float4* __restrict__ tab,
    float* __restrict__ out, int B, int quadB)
{
    __shared__ float4 sT[TN];      // 8 KB

    const int p = blockIdx.x * BLOCK + threadIdx.x;
    const bool valid = p < quadB;

    // Prefetch inputs FIRST so their HBM latency overlaps table staging+sync.
    float4 uu  = make_float4(0.f, 0.f, 0.f, 0.f);
    float4 s01 = make_float4(0.f, 0.f, 0.f, 0.f);
    float4 s23 = make_float4(0.f, 0.f, 0.f, 0.f);
    if (valid) {
        uu  = ((const float4*)inputs)[p];          // elems 4p..4p+3
        s01 = ((const float4*)states)[2 * p];      // rows 4p, 4p+1
        s23 = ((const float4*)states)[2 * p + 1];  // rows 4p+2, 4p+3
    }

    #pragma unroll
    for (int t = threadIdx.x; t < TN; t += BLOCK) sT[t] = tab[t];
    __syncthreads();

    const float INVH = (float)(TN - 1) / (YMAX - YMIN);
    if (valid) {
        float2 r0 = rk4_elem(uu.x, s01.y, sT, INVH);
        float2 r1 = rk4_elem(uu.y, s01.w, sT, INVH);
        float2 r2 = rk4_elem(uu.z, s23.y, sT, INVH);
        float2 r3 = rk4_elem(uu.w, s23.w, sT, INVH);
        ((float4*)out)[2 * p]     = make_float4(r0.x, r0.y, r1.x, r1.y);
        ((float4*)out)[2 * p + 1] = make_float4(r2.x, r2.y, r3.x, r3.y);
    }

    // B % 4 tail (not hit for B = 1048576)
    if (p == 0) {
        for (int i = B & ~3; i < B; ++i) {
            float2 r = rk4_elem(inputs[i], ((const float2*)states)[i].y, sT, INVH);
            ((float2*)out)[i] = r;
        }
    }
}

extern "C" void kernel_launch(void* const* d_in, const int* in_sizes, int n_in,
                              void* d_out, int out_size, void* d_ws, size_t ws_size,
                              hipStream_t stream) {
    const float* inputs  = (const float*)d_in[0];
    const float* states  = (const float*)d_in[1];
    const float* centers = (const float*)d_in[2];
    const float* gammas  = (const float*)d_in[3];
    const float* weights = (const float*)d_in[4];
    float* out = (float*)d_out;
    float4* tab = (float4*)d_ws;               // TN * 16 B = 8 KB scratch
    const int B = in_sizes[0];

    build_table_kernel<<<(TN * 64 + 255) / 256, 256, 0, stream>>>(
        centers, gammas, weights, tab);

    const int quadB = B >> 2;
    int grid = (quadB + BLOCK - 1) / BLOCK;
    if (grid < 1) grid = 1;
    rk4_tab_kernel<<<grid, BLOCK, 0, stream>>>(
        inputs, states, tab, out, B, quadB);
}